// Round 9
// baseline (182.039 us; speedup 1.0000x reference)
//
#include <hip/hip_runtime.h>
#include <hip/hip_bf16.h>
#include <stdint.h>

#define NH 16
#define HDIM 64
#define NB 2
#define NSEQ 2048
#define DM 1024
#define MROWS (NB * NSEQ)   // 4096

typedef __attribute__((ext_vector_type(8))) short bf16x8;
typedef __attribute__((ext_vector_type(4))) float f32x4;

#define MFMA32(a, b, c) __builtin_amdgcn_mfma_f32_16x16x32_bf16(a, b, c, 0, 0, 0)

static __device__ __forceinline__ unsigned short f2bf(float f) {
    union { float f; unsigned u; } v;
    v.f = f;
    unsigned r = v.u + 0x7fffu + ((v.u >> 16) & 1u);   // RNE
    return (unsigned short)(r >> 16);
}

static __device__ __forceinline__ unsigned pack2bf(float a, float b) {
#if __has_builtin(__builtin_amdgcn_cvt_pk_bf16_f32)
    typedef __attribute__((ext_vector_type(2))) __bf16 bf2_t;
    union { bf2_t v; unsigned u; } c;
    c.v = __builtin_amdgcn_cvt_pk_bf16_f32(a, b);
    return c.u;
#else
    return (unsigned)f2bf(a) | ((unsigned)f2bf(b) << 16);
#endif
}

static __device__ __forceinline__ float fexp2(float x) {
#if __has_builtin(__builtin_amdgcn_exp2f)
    return __builtin_amdgcn_exp2f(x);
#else
    return exp2f(x);
#endif
}

typedef __attribute__((address_space(1))) void* gas_ptr;
typedef __attribute__((address_space(3))) void* las_ptr;

// async global->LDS, 16B per lane. LDS dest must be wave-uniform base + lane*16.
static __device__ __forceinline__ void load16_lds(const void* g, void* l) {
    __builtin_amdgcn_global_load_lds((gas_ptr)(uintptr_t)g, (las_ptr)(uintptr_t)l,
                                     16, 0, 0);
}

// ---------------------------------------------------------------------------
// Convert: x -> bf16 (blocks 0..1023), weights -> bf16 transposed via LDS
// tile transpose (blocks 1024..2047). (unchanged)
// ---------------------------------------------------------------------------
__global__ __launch_bounds__(256) void convert_kernel(
    const float* __restrict__ x,
    const float* __restrict__ wq, const float* __restrict__ wk,
    const float* __restrict__ wv, const float* __restrict__ wo,
    unsigned short* __restrict__ xb,
    unsigned short* __restrict__ wqkvt,
    unsigned short* __restrict__ wot)
{
    __shared__ unsigned short Ts[64][66];
    int t = threadIdx.x;
    int bx = blockIdx.x;
    if (bx < 1024) {
        const float4* xs = (const float4*)x + (long)bx * 1024;
        unsigned short* xd = xb + (long)bx * 4096;
#pragma unroll
        for (int i = 0; i < 4; i++) {
            float4 v = xs[i * 256 + t];
            ushort4 o;
            o.x = f2bf(v.x); o.y = f2bf(v.y); o.z = f2bf(v.z); o.w = f2bf(v.w);
            *(ushort4*)(xd + (i * 256 + t) * 4) = o;
        }
        return;
    }
    int wi = bx - 1024;
    int wsel = wi >> 8;                 // 0..3 = q,k,v,o
    int tile = wi & 255;
    int k0 = (tile >> 4) * 64, c0 = (tile & 15) * 64;
    const float* w = (wsel == 0) ? wq : (wsel == 1) ? wk : (wsel == 2) ? wv : wo;
    int lr = t >> 6, lc = t & 63;
#pragma unroll
    for (int rr = 0; rr < 16; rr++) {
        int row = rr * 4 + lr;
        Ts[row][lc] = f2bf(w[(long)(k0 + row) * DM + c0 + lc]);
    }
    __syncthreads();
    unsigned short* dst = (wsel == 3) ? wot : (wqkvt + (long)wsel * DM * DM);
#pragma unroll
    for (int rr = 0; rr < 16; rr++) {
        int crow = rr * 4 + lr;
        dst[(long)(c0 + crow) * DM + k0 + lc] = Ts[lc][crow];
    }
}

// ---------------------------------------------------------------------------
// DOUBLE-BUFFERED GEMM core (unchanged structure; round-13 swizzle kept).
// ---------------------------------------------------------------------------
template<int MR>
static __device__ __forceinline__ void gemm_core_db(
    const unsigned short* __restrict__ A,
    const unsigned short* __restrict__ Bt,
    int m0, int n0,
    unsigned short* __restrict__ As,   // [2][MR*32*32] shorts
    unsigned short* __restrict__ Bs,   // [2][128*32] shorts
    f32x4 (&acc)[MR][4])
{
    constexpr int MT  = MR * 32;       // M tile rows
    constexpr int ASZ = MT * 32;       // shorts per A buffer
    constexpr int BSZ = 128 * 32;      // shorts per B buffer
    constexpr int NA  = MT / 64;       // A load16 per thread (2 or 1)

    int t = threadIdx.x;
    int lane = t & 63;
    int wave = t >> 6;
    int l16 = lane & 15, quad = lane >> 4;
    int wm = wave >> 1, wn = wave & 1;

    const char* gA[NA];
#pragma unroll
    for (int i = 0; i < NA; i++) {
        int b = i * 256 + t;
        int row = b >> 2, g = (b & 3) ^ ((row >> 1) & 3);
        gA[i] = (const char*)(A + (long)(m0 + row) * DM) + g * 16;
    }
    const char* gB[2];
#pragma unroll
    for (int i = 0; i < 2; i++) {
        int b = i * 256 + t;
        int row = b >> 2, g = (b & 3) ^ ((row >> 1) & 3);
        gB[i] = (const char*)(Bt + (long)(n0 + row) * DM) + g * 16;
    }

    int sread = quad ^ ((l16 >> 1) & 3);
    int faOff = (wm * (MT / 2) + l16) * 32 + sread * 8;
    int fbOff = (wn * 64 + l16) * 32 + sread * 8;

    // stage k=0 into buffer 0
#pragma unroll
    for (int i = 0; i < NA; i++)
        load16_lds(gA[i], (char*)As + i * 4096 + t * 16);
#pragma unroll
    for (int i = 0; i < 2; i++)
        load16_lds(gB[i], (char*)Bs + i * 4096 + t * 16);

    for (int kk = 0; kk < DM; kk += 32) {
        int cur = (kk >> 5) & 1;
        __syncthreads();                       // stage(kk) landed; buf free
        if (kk + 32 < DM) {
            int nxt = cur ^ 1;
            char* abuf = (char*)(As + nxt * ASZ);
            char* bbuf = (char*)(Bs + nxt * BSZ);
#pragma unroll
            for (int i = 0; i < NA; i++)
                load16_lds(gA[i] + (kk + 32) * 2, abuf + i * 4096 + t * 16);
#pragma unroll
            for (int i = 0; i < 2; i++)
                load16_lds(gB[i] + (kk + 32) * 2, bbuf + i * 4096 + t * 16);
        }
        const unsigned short* fa = As + cur * ASZ + faOff;
        const unsigned short* fb = Bs + cur * BSZ + fbOff;
        bf16x8 af[MR], bf[4];
#pragma unroll
        for (int r = 0; r < MR; r++) af[r] = *(const bf16x8*)(fa + r * 16 * 32);
#pragma unroll
        for (int c = 0; c < 4; c++) bf[c] = *(const bf16x8*)(fb + c * 16 * 32);
#pragma unroll
        for (int r = 0; r < MR; r++)
#pragma unroll
            for (int c = 0; c < 4; c++)
                acc[r][c] = MFMA32(af[r], bf[c], acc[r][c]);
    }
}

// ---------------------------------------------------------------------------
// Fused QKV GEMM, 128x128 tile, XCD-bijective swizzle (R2-verified).
// ---------------------------------------------------------------------------
__global__ __launch_bounds__(256, 3) void qkv_gemm_kernel(
    const unsigned short* __restrict__ A,
    const unsigned short* __restrict__ Bt,
    unsigned short* __restrict__ Qo, unsigned short* __restrict__ Ko,
    unsigned short* __restrict__ Vt)
{
    __shared__ unsigned short As[2][128 * 32];
    __shared__ unsigned short Bs[2][128 * 32];
    __shared__ unsigned short Tw[4][16][72];

    f32x4 acc[4][4] = {};
    int id = blockIdx.y * 24 + blockIdx.x;        // nwg = 32*24 = 768
    id = (id & 7) * 96 + (id >> 3);               // XCD-bijective swizzle
    int m0 = (id / 24) * 128, n0 = (id % 24) * 128;
    gemm_core_db<4>(A, Bt, m0, n0, &As[0][0], &Bs[0][0], acc);

    int t = threadIdx.x, wave = t >> 6, lane = t & 63;
    int l16 = lane & 15, quad = lane >> 4;
    int wm = wave >> 1, wn = wave & 1;
    int rg0 = m0 + wm * 64;
    int cg0 = n0 + wn * 64;
    int z = cg0 >> 10;
    int b_ = rg0 >> 11;
    int nb0 = rg0 & (NSEQ - 1);
    int h = (cg0 & 1023) >> 6;
    long bh = (long)(b_ * NH + h);

    if (z < 2) {
        unsigned short* dst = (z == 0 ? Qo : Ko) + bh * NSEQ * HDIM;
#pragma unroll
        for (int r = 0; r < 4; r++)
#pragma unroll
            for (int reg = 0; reg < 4; reg++) {
                long rowb = (long)(nb0 + r * 16 + quad * 4 + reg) * HDIM;
#pragma unroll
                for (int c = 0; c < 4; c++)
                    dst[rowb + c * 16 + l16] = f2bf(acc[r][c][reg]);
            }
    } else {
        unsigned short* dst = Vt + bh * HDIM * NSEQ;
#pragma unroll
        for (int c = 0; c < 4; c++) {
#pragma unroll
            for (int r = 0; r < 4; r++) {
                ushort4 u;
                u.x = f2bf(acc[r][c][0]); u.y = f2bf(acc[r][c][1]);
                u.z = f2bf(acc[r][c][2]); u.w = f2bf(acc[r][c][3]);
                *(ushort4*)&Tw[wave][l16][r * 16 + quad * 4] = u;   // [hd][n]
            }
#pragma unroll
            for (int j = 0; j < 4; j++) {
                int lrow = j * 4 + quad;
                ushort4 u = *(const ushort4*)&Tw[wave][lrow][l16 * 4];
                *(ushort4*)(dst + (long)(c * 16 + lrow) * NSEQ + nb0 + l16 * 4) = u;
            }
        }
    }
}

// ---------------------------------------------------------------------------
// fixed-shift softmax, in-place exp (R2-verified).
// ---------------------------------------------------------------------------
static __device__ __forceinline__ void softmax_fixed(
    f32x4* s, bool mask, int qb, int kb, float sc2, float mrow,
    f32x4& l_vec, unsigned pbu[2][4], int l16, int quad)
{
    if (mask) {
        int fdm = qb + l16 - kb - quad * 4;   // key offset tt*16+r must be <= fdm
#pragma unroll
        for (int tt = 0; tt < 4; tt++)
#pragma unroll
            for (int r = 0; r < 4; r++)
                if (tt * 16 + r > fdm) s[tt][r] = -3e38f;
    }
#pragma unroll
    for (int tt = 0; tt < 4; tt++)
#pragma unroll
        for (int r = 0; r < 4; r++)
            s[tt][r] = fexp2(s[tt][r] * sc2 - mrow);   // v_fma + v_exp, in-place
#pragma unroll
    for (int r = 0; r < 4; r++)
        l_vec[r] += (s[0][r] + s[1][r]) + (s[2][r] + s[3][r]);

#pragma unroll
    for (int p = 0; p < 2; p++) {
        pbu[p][0] = pack2bf(s[2 * p][0],     s[2 * p][1]);
        pbu[p][1] = pack2bf(s[2 * p][2],     s[2 * p][3]);
        pbu[p][2] = pack2bf(s[2 * p + 1][0], s[2 * p + 1][1]);
        pbu[p][3] = pack2bf(s[2 * p + 1][2], s[2 * p + 1][3]);
    }
}

// ---------------------------------------------------------------------------
// Flash attention v15: un-paired blocks (R8 structure) + 3-DEEP STAGING
// PIPELINE with counted vmcnt + raw barrier (T3/T4).
// Model from R2/R7/R8 cross-profiles: makespan = diagonal block's serial
// chain of (stall + compute) per chunk; stall ~1250cy = staging latency not
// covered by ONE compute phase + __syncthreads' vmcnt(0) drain of the
// just-issued prefetch. Fix: 3 buffers; stage(c+2) issued at iter c -> two
// compute phases of cover; barrier waits only for chunk c via
// s_waitcnt vmcnt(4) (the newest 4 loads = stage(c+1) stay in flight).
// Last iter (stage(c+1) not issued) uses vmcnt(0) -- block-uniform branch.
// sched_barrier(0) after the raw barrier fences ds_read hoisting (rule 18).
// WAR on buffer reuse: all waves' compute(c-1) operand reads are consumed
// by issued MFMAs before crossing B_c. LDS 3x16KB = 48KB -> 3 blocks/CU.
// ---------------------------------------------------------------------------
__global__ __launch_bounds__(256, 3) void attn_kernel(
    const unsigned short* __restrict__ Q,
    const unsigned short* __restrict__ K,
    const unsigned short* __restrict__ Vt,
    unsigned short* __restrict__ ctx)
{
    // [buf][ K: 4096 shorts (64k x 64d) | V: 4096 shorts (64hd x 64k) ]
    __shared__ unsigned short KV[3][8192];

    int t = threadIdx.x, w = t >> 6, lane = t & 63;
    int l16 = lane & 15, quad = lane >> 4;
    int r7 = l16 & 7;
    int bh = blockIdx.x;            // XCD = bh % 8 (L2 locality)
    int b_ = bh >> 4, h = bh & 15;
    int tile = blockIdx.y;          // 64q tile 0..31
    int qb = tile * 64 + w * 16;    // wave's 16 q rows
    int nch = tile + 1;             // 64-key chunks needed (<= diagonal)

    const unsigned short* Kg  = K  + (long)bh * NSEQ * HDIM;
    const unsigned short* Vtg = Vt + (long)bh * HDIM * NSEQ;

    const float log2e = 1.44269504f;
    float slope = exp2f(-0.5f * (float)(h + 1));
    float sc2 = 0.125f * log2e;     // scale * log2(e)
    float ss2 = slope * sc2;

    const unsigned short* qp = Q + ((long)bh * NSEQ + qb + l16) * HDIM + quad * 8;
    bf16x8 aq0 = *(const bf16x8*)qp;
    bf16x8 aq1 = *(const bf16x8*)(qp + 32);

    // alibi C-init, slim form: ci4[r] = slope*(quad*4+r); per-tt add slope*16*tt
    f32x4 ci4;
#pragma unroll
    for (int r = 0; r < 4; r++)
        ci4[r] = slope * (float)(quad * 4 + r);
    float s16 = slope * 16.0f;

    f32x4 lv = {};
    f32x4 o[4] = {};

    // staging: 256 threads x 16B = 4KB/pass; 2 passes per 8KB (rows 0-31, 32-63)
    int row = t >> 3, sp = t & 7, sw = sp ^ (row & 7);
    const unsigned short* gk = Kg + row * HDIM + sw * 8;
    const unsigned short* gv = Vtg + (long)row * NSEQ + sw * 8;

    {   // prologue: stage chunk 0 (and chunk 1 if needed)
        unsigned short* buf = KV[0];
        load16_lds(gk,             buf + t * 8);
        load16_lds(gk + 32 * HDIM, buf + 2048 + t * 8);
        load16_lds(gv,             buf + 4096 + t * 8);
        load16_lds(gv + 32 * NSEQ, buf + 6144 + t * 8);
    }
    if (nch > 1) {
        unsigned short* buf = KV[1];
        const unsigned short* kp = gk + (long)64 * HDIM;
        const unsigned short* vp = gv + 64;
        load16_lds(kp,             buf + t * 8);
        load16_lds(kp + 32 * HDIM, buf + 2048 + t * 8);
        load16_lds(vp,             buf + 4096 + t * 8);
        load16_lds(vp + 32 * NSEQ, buf + 6144 + t * 8);
    }

    int cur = 0;
    for (int c = 0; c < nch; c++) {
        // wait for stage(c) only; stage(c+1)'s 4 loads may stay in flight
        if (c + 1 < nch) {
            asm volatile("s_waitcnt vmcnt(4)" ::: "memory");
        } else {
            asm volatile("s_waitcnt vmcnt(0)" ::: "memory");
        }
        __builtin_amdgcn_s_barrier();
        __builtin_amdgcn_sched_barrier(0);

        if (c + 2 < nch) {
            int pre = cur + 2; if (pre >= 3) pre -= 3;
            unsigned short* buf = KV[pre];
            int kb2 = (c + 2) * 64;
            const unsigned short* kp = gk + (long)kb2 * HDIM;
            const unsigned short* vp = gv + kb2;
            load16_lds(kp,             buf + t * 8);
            load16_lds(kp + 32 * HDIM, buf + 2048 + t * 8);
            load16_lds(vp,             buf + 4096 + t * 8);
            load16_lds(vp + 32 * NSEQ, buf + 6144 + t * 8);
        }

        const unsigned short* Ks = KV[cur];
        const unsigned short* Vs = KV[cur] + 4096;
        int kb = c * 64;

        // ---- S^T = K·Q^T + alibi (one 16-q slice per wave)
        f32x4 s[4];
        __builtin_amdgcn_s_setprio(1);
#pragma unroll
        for (int tt = 0; tt < 4; tt++) {
            int rr = tt * 16 + l16;
            bf16x8 k0 = *(const bf16x8*)(Ks + (rr * 8 + (quad ^ r7)) * 8);
            bf16x8 k1 = *(const bf16x8*)(Ks + (rr * 8 + ((quad + 4) ^ r7)) * 8);
            f32x4 cz;
#pragma unroll
            for (int r = 0; r < 4; r++)
                cz[r] = ci4[r] + (float)tt * s16;
            f32x4 z = MFMA32(k0, aq0, cz);
            s[tt] = MFMA32(k1, aq1, z);
        }
        __builtin_amdgcn_s_setprio(0);

        float mrow = ss2 * (float)(qb + l16 - kb);
        unsigned pb[2][4];
        softmax_fixed(s, kb + 63 > qb, qb, kb, sc2, mrow, lv, pb, l16, quad);

        // ---- O^T += V^T·P^T (verified pattern)
        int q2 = quad >> 1, q1b = (quad & 1) << 3;
        __builtin_amdgcn_s_setprio(1);
#pragma unroll
        for (int cb = 0; cb < 4; cb++) {
            int rd = cb * 16 + l16;
            const char* vrow = (const char*)(Vs + rd * 64);
            int x7 = rd & 7;
#pragma unroll
            for (int p = 0; p < 2; p++) {
                union { bf16x8 v; uint2 u2[2]; } a;
                int sb0 = 4 * p + q2;
                int sb1 = 4 * p + 2 + q2;
                a.u2[0] = *(const uint2*)(vrow + ((sb0 ^ x7) << 4) + q1b);
                a.u2[1] = *(const uint2*)(vrow + ((sb1 ^ x7) << 4) + q1b);
                union { unsigned u[4]; bf16x8 v; } bv;
#pragma unroll
                for (int i = 0; i < 4; i++) bv.u[i] = pb[p][i];
                o[cb] = MFMA32(a.v, bv.v, o[cb]);
            }
        }
        __builtin_amdgcn_s_setprio(0);

        cur += 1; if (cur == 3) cur = 0;
    }

    // ---- final l reduction + normalize, store ctx [b, n=q, h, d]
    {
        float lt = (lv[0] + lv[1]) + (lv[2] + lv[3]);
        lt += __shfl_xor(lt, 16);
        lt += __shfl_xor(lt, 32);
        float inv = 1.0f / lt;
        long base = (((long)b_ * NSEQ + (qb + l16)) * NH + h) * HDIM + quad * 4;
#pragma unroll
        for (int cb = 0; cb < 4; cb++) {
            uint2 u;
            u.x = pack2bf(o[cb][0] * inv, o[cb][1] * inv);
            u.y = pack2bf(o[cb][2] * inv, o[cb][3] * inv);
            *(uint2*)(ctx + base + cb * 16) = u;
        }
    }
}

// ---------------------------------------------------------------------------
// Output projection, 64x128 tile, XCD-bijective swizzle, (256,4). (R2)
// ---------------------------------------------------------------------------
__global__ __launch_bounds__(256, 4) void out_gemm_kernel(
    const unsigned short* __restrict__ A,
    const unsigned short* __restrict__ Bt,
    const float* __restrict__ bias,
    float* __restrict__ out)
{
    __shared__ unsigned short As[2][64 * 32];
    __shared__ unsigned short Bs[2][128 * 32];
    f32x4 acc[2][4] = {};
    int id = blockIdx.y * 8 + blockIdx.x;         // nwg = 64*8 = 512
    id = (id & 7) * 64 + (id >> 3);               // XCD-bijective swizzle
    int m0 = (id >> 3) * 64, n0 = (id & 7) * 128;
    gemm_core_db<2>(A, Bt, m0, n0, &As[0][0], &Bs[0][0], acc);

    int t = threadIdx.x, wave = t >> 6, lane = t & 63;
    int l16 = lane & 15, quad = lane >> 4;
    int wm = wave >> 1, wn = wave & 1;
    int rg0 = m0 + wm * 32, cg0 = n0 + wn * 64;
#pragma unroll
    for (int c = 0; c < 4; c++) {
        float bc = bias[cg0 + c * 16 + l16];
#pragma unroll
        for (int r = 0; r < 2; r++)
#pragma unroll
            for (int reg = 0; reg < 4; reg++)
                out[(long)(rg0 + r * 16 + quad * 4 + reg) * DM + cg0 + c * 16 + l16] =
                    acc[r][c][reg] + bc;
    }
}

// ---------------------------------------------------------------------------
extern "C" void kernel_launch(void* const* d_in, const int* in_sizes, int n_in,
                              void* d_out, int out_size, void* d_ws, size_t ws_size,
                              hipStream_t stream)
{
    const float* x  = (const float*)d_in[0];
    const float* wq = (const float*)d_in[1];
    const float* wk = (const float*)d_in[2];
    const float* wv = (const float*)d_in[3];
    const float* wo = (const float*)d_in[4];
    const float* bo = (const float*)d_in[5];

    char* ws = (char*)d_ws;
    unsigned short* xb    = (unsigned short*)(ws);                 // 8 MiB
    unsigned short* wqkvt = (unsigned short*)(ws + (8L  << 20));   // 6 MiB [3072][1024]
    unsigned short* wot   = (unsigned short*)(ws + (14L << 20));   // 2 MiB
    unsigned short* Qb    = (unsigned short*)(ws + (16L << 20));   // 8 MiB
    unsigned short* Kb    = (unsigned short*)(ws + (24L << 20));   // 8 MiB
    unsigned short* Vt    = (unsigned short*)(ws + (32L << 20));   // 8 MiB
    unsigned short* ctx   = (unsigned short*)(ws + (40L << 20));   // 8 MiB
    float* out = (float*)d_out;

    convert_kernel<<<2048, 256, 0, stream>>>(x, wq, wk, wv, wo, xb, wqkvt, wot);

    qkv_gemm_kernel<<<dim3(3 * DM / 128, MROWS / 128), 256, 0, stream>>>(
        xb, wqkvt, Qb, Kb, Vt);

    attn_kernel<<<dim3(NB * NH, 32), 256, 0, stream>>>(Qb, Kb, Vt, ctx);

    out_gemm_kernel<<<dim3(DM / 128, MROWS / 64), 256, 0, stream>>>(
        ctx, wot, bo, out);
}

// Round 10
// 168.437 us; speedup vs baseline: 1.0808x; 1.0808x over previous
//
#include <hip/hip_runtime.h>
#include <hip/hip_bf16.h>
#include <stdint.h>

#define NH 16
#define HDIM 64
#define NB 2
#define NSEQ 2048
#define DM 1024
#define MROWS (NB * NSEQ)   // 4096

typedef __attribute__((ext_vector_type(8))) short bf16x8;
typedef __attribute__((ext_vector_type(4))) float f32x4;

#define MFMA32(a, b, c) __builtin_amdgcn_mfma_f32_16x16x32_bf16(a, b, c, 0, 0, 0)

static __device__ __forceinline__ unsigned short f2bf(float f) {
    union { float f; unsigned u; } v;
    v.f = f;
    unsigned r = v.u + 0x7fffu + ((v.u >> 16) & 1u);   // RNE
    return (unsigned short)(r >> 16);
}

static __device__ __forceinline__ unsigned pack2bf(float a, float b) {
#if __has_builtin(__builtin_amdgcn_cvt_pk_bf16_f32)
    typedef __attribute__((ext_vector_type(2))) __bf16 bf2_t;
    union { bf2_t v; unsigned u; } c;
    c.v = __builtin_amdgcn_cvt_pk_bf16_f32(a, b);
    return c.u;
#else
    return (unsigned)f2bf(a) | ((unsigned)f2bf(b) << 16);
#endif
}

static __device__ __forceinline__ float fexp2(float x) {
#if __has_builtin(__builtin_amdgcn_exp2f)
    return __builtin_amdgcn_exp2f(x);
#else
    return exp2f(x);
#endif
}

typedef __attribute__((address_space(1))) void* gas_ptr;
typedef __attribute__((address_space(3))) void* las_ptr;

// async global->LDS, 16B per lane. LDS dest must be wave-uniform base + lane*16.
static __device__ __forceinline__ void load16_lds(const void* g, void* l) {
    __builtin_amdgcn_global_load_lds((gas_ptr)(uintptr_t)g, (las_ptr)(uintptr_t)l,
                                     16, 0, 0);
}

// ---------------------------------------------------------------------------
// Convert: x -> bf16 (blocks 0..1023), weights -> bf16 transposed via LDS
// tile transpose (blocks 1024..2047). (unchanged)
// ---------------------------------------------------------------------------
__global__ __launch_bounds__(256) void convert_kernel(
    const float* __restrict__ x,
    const float* __restrict__ wq, const float* __restrict__ wk,
    const float* __restrict__ wv, const float* __restrict__ wo,
    unsigned short* __restrict__ xb,
    unsigned short* __restrict__ wqkvt,
    unsigned short* __restrict__ wot)
{
    __shared__ unsigned short Ts[64][66];
    int t = threadIdx.x;
    int bx = blockIdx.x;
    if (bx < 1024) {
        const float4* xs = (const float4*)x + (long)bx * 1024;
        unsigned short* xd = xb + (long)bx * 4096;
#pragma unroll
        for (int i = 0; i < 4; i++) {
            float4 v = xs[i * 256 + t];
            ushort4 o;
            o.x = f2bf(v.x); o.y = f2bf(v.y); o.z = f2bf(v.z); o.w = f2bf(v.w);
            *(ushort4*)(xd + (i * 256 + t) * 4) = o;
        }
        return;
    }
    int wi = bx - 1024;
    int wsel = wi >> 8;                 // 0..3 = q,k,v,o
    int tile = wi & 255;
    int k0 = (tile >> 4) * 64, c0 = (tile & 15) * 64;
    const float* w = (wsel == 0) ? wq : (wsel == 1) ? wk : (wsel == 2) ? wv : wo;
    int lr = t >> 6, lc = t & 63;
#pragma unroll
    for (int rr = 0; rr < 16; rr++) {
        int row = rr * 4 + lr;
        Ts[row][lc] = f2bf(w[(long)(k0 + row) * DM + c0 + lc]);
    }
    __syncthreads();
    unsigned short* dst = (wsel == 3) ? wot : (wqkvt + (long)wsel * DM * DM);
#pragma unroll
    for (int rr = 0; rr < 16; rr++) {
        int crow = rr * 4 + lr;
        dst[(long)(c0 + crow) * DM + k0 + lc] = Ts[lc][crow];
    }
}

// ---------------------------------------------------------------------------
// DOUBLE-BUFFERED GEMM core (unchanged structure; round-13 swizzle kept).
// ---------------------------------------------------------------------------
template<int MR>
static __device__ __forceinline__ void gemm_core_db(
    const unsigned short* __restrict__ A,
    const unsigned short* __restrict__ Bt,
    int m0, int n0,
    unsigned short* __restrict__ As,   // [2][MR*32*32] shorts
    unsigned short* __restrict__ Bs,   // [2][128*32] shorts
    f32x4 (&acc)[MR][4])
{
    constexpr int MT  = MR * 32;       // M tile rows
    constexpr int ASZ = MT * 32;       // shorts per A buffer
    constexpr int BSZ = 128 * 32;      // shorts per B buffer
    constexpr int NA  = MT / 64;       // A load16 per thread (2 or 1)

    int t = threadIdx.x;
    int lane = t & 63;
    int wave = t >> 6;
    int l16 = lane & 15, quad = lane >> 4;
    int wm = wave >> 1, wn = wave & 1;

    const char* gA[NA];
#pragma unroll
    for (int i = 0; i < NA; i++) {
        int b = i * 256 + t;
        int row = b >> 2, g = (b & 3) ^ ((row >> 1) & 3);
        gA[i] = (const char*)(A + (long)(m0 + row) * DM) + g * 16;
    }
    const char* gB[2];
#pragma unroll
    for (int i = 0; i < 2; i++) {
        int b = i * 256 + t;
        int row = b >> 2, g = (b & 3) ^ ((row >> 1) & 3);
        gB[i] = (const char*)(Bt + (long)(n0 + row) * DM) + g * 16;
    }

    int sread = quad ^ ((l16 >> 1) & 3);
    int faOff = (wm * (MT / 2) + l16) * 32 + sread * 8;
    int fbOff = (wn * 64 + l16) * 32 + sread * 8;

    // stage k=0 into buffer 0
#pragma unroll
    for (int i = 0; i < NA; i++)
        load16_lds(gA[i], (char*)As + i * 4096 + t * 16);
#pragma unroll
    for (int i = 0; i < 2; i++)
        load16_lds(gB[i], (char*)Bs + i * 4096 + t * 16);

    for (int kk = 0; kk < DM; kk += 32) {
        int cur = (kk >> 5) & 1;
        __syncthreads();                       // stage(kk) landed; buf free
        if (kk + 32 < DM) {
            int nxt = cur ^ 1;
            char* abuf = (char*)(As + nxt * ASZ);
            char* bbuf = (char*)(Bs + nxt * BSZ);
#pragma unroll
            for (int i = 0; i < NA; i++)
                load16_lds(gA[i] + (kk + 32) * 2, abuf + i * 4096 + t * 16);
#pragma unroll
            for (int i = 0; i < 2; i++)
                load16_lds(gB[i] + (kk + 32) * 2, bbuf + i * 4096 + t * 16);
        }
        const unsigned short* fa = As + cur * ASZ + faOff;
        const unsigned short* fb = Bs + cur * BSZ + fbOff;
        bf16x8 af[MR], bf[4];
#pragma unroll
        for (int r = 0; r < MR; r++) af[r] = *(const bf16x8*)(fa + r * 16 * 32);
#pragma unroll
        for (int c = 0; c < 4; c++) bf[c] = *(const bf16x8*)(fb + c * 16 * 32);
#pragma unroll
        for (int r = 0; r < MR; r++)
#pragma unroll
            for (int c = 0; c < 4; c++)
                acc[r][c] = MFMA32(af[r], bf[c], acc[r][c]);
    }
}

// ---------------------------------------------------------------------------
// Fused QKV GEMM, 128x128 tile, XCD-bijective swizzle (R2-verified).
// ---------------------------------------------------------------------------
__global__ __launch_bounds__(256, 3) void qkv_gemm_kernel(
    const unsigned short* __restrict__ A,
    const unsigned short* __restrict__ Bt,
    unsigned short* __restrict__ Qo, unsigned short* __restrict__ Ko,
    unsigned short* __restrict__ Vt)
{
    __shared__ unsigned short As[2][128 * 32];
    __shared__ unsigned short Bs[2][128 * 32];
    __shared__ unsigned short Tw[4][16][72];

    f32x4 acc[4][4] = {};
    int id = blockIdx.y * 24 + blockIdx.x;        // nwg = 32*24 = 768
    id = (id & 7) * 96 + (id >> 3);               // XCD-bijective swizzle
    int m0 = (id / 24) * 128, n0 = (id % 24) * 128;
    gemm_core_db<4>(A, Bt, m0, n0, &As[0][0], &Bs[0][0], acc);

    int t = threadIdx.x, wave = t >> 6, lane = t & 63;
    int l16 = lane & 15, quad = lane >> 4;
    int wm = wave >> 1, wn = wave & 1;
    int rg0 = m0 + wm * 64;
    int cg0 = n0 + wn * 64;
    int z = cg0 >> 10;
    int b_ = rg0 >> 11;
    int nb0 = rg0 & (NSEQ - 1);
    int h = (cg0 & 1023) >> 6;
    long bh = (long)(b_ * NH + h);

    if (z < 2) {
        unsigned short* dst = (z == 0 ? Qo : Ko) + bh * NSEQ * HDIM;
#pragma unroll
        for (int r = 0; r < 4; r++)
#pragma unroll
            for (int reg = 0; reg < 4; reg++) {
                long rowb = (long)(nb0 + r * 16 + quad * 4 + reg) * HDIM;
#pragma unroll
                for (int c = 0; c < 4; c++)
                    dst[rowb + c * 16 + l16] = f2bf(acc[r][c][reg]);
            }
    } else {
        unsigned short* dst = Vt + bh * HDIM * NSEQ;
#pragma unroll
        for (int c = 0; c < 4; c++) {
#pragma unroll
            for (int r = 0; r < 4; r++) {
                ushort4 u;
                u.x = f2bf(acc[r][c][0]); u.y = f2bf(acc[r][c][1]);
                u.z = f2bf(acc[r][c][2]); u.w = f2bf(acc[r][c][3]);
                *(ushort4*)&Tw[wave][l16][r * 16 + quad * 4] = u;   // [hd][n]
            }
#pragma unroll
            for (int j = 0; j < 4; j++) {
                int lrow = j * 4 + quad;
                ushort4 u = *(const ushort4*)&Tw[wave][lrow][l16 * 4];
                *(ushort4*)(dst + (long)(c * 16 + lrow) * NSEQ + nb0 + l16 * 4) = u;
            }
        }
    }
}

// ---------------------------------------------------------------------------
// fixed-shift softmax, in-place exp (R2-verified).
// ---------------------------------------------------------------------------
static __device__ __forceinline__ void softmax_fixed(
    f32x4* s, bool mask, int qb, int kb, float sc2, float mrow,
    f32x4& l_vec, unsigned pbu[2][4], int l16, int quad)
{
    if (mask) {
        int fdm = qb + l16 - kb - quad * 4;   // key offset tt*16+r must be <= fdm
#pragma unroll
        for (int tt = 0; tt < 4; tt++)
#pragma unroll
            for (int r = 0; r < 4; r++)
                if (tt * 16 + r > fdm) s[tt][r] = -3e38f;
    }
#pragma unroll
    for (int tt = 0; tt < 4; tt++)
#pragma unroll
        for (int r = 0; r < 4; r++)
            s[tt][r] = fexp2(s[tt][r] * sc2 - mrow);   // v_fma + v_exp, in-place
#pragma unroll
    for (int r = 0; r < 4; r++)
        l_vec[r] += (s[0][r] + s[1][r]) + (s[2][r] + s[3][r]);

#pragma unroll
    for (int p = 0; p < 2; p++) {
        pbu[p][0] = pack2bf(s[2 * p][0],     s[2 * p][1]);
        pbu[p][1] = pack2bf(s[2 * p][2],     s[2 * p][3]);
        pbu[p][2] = pack2bf(s[2 * p + 1][0], s[2 * p + 1][1]);
        pbu[p][3] = pack2bf(s[2 * p + 1][2], s[2 * p + 1][3]);
    }
}

// ---------------------------------------------------------------------------
// Flash attention v16: one block per (bh, 128q tile), 8 waves ALL on the
// same tile (qb = tile*128 + w*16) -> zero idle waves. nch = tile+1 chunks
// of 128 keys, R2's verified loop body (__syncthreads dbuf, same staging,
// same compute). Tile permutation tile = y<8 ? y : 23-y makes the two
// blocks a CU receives under in-order round-robin (y, y+8) sum to EXACTLY
// 17 barrier-iterations -- vs R2's avg 25 / max 32. Model (fits R2/R7/R8/
// R9): makespan = per-CU barrier-iters x (stall ~500cy + compute). LDS
// 64KB -> 2 blocks/CU, all 512 blocks resident.
// ---------------------------------------------------------------------------
__global__ __launch_bounds__(512, 4) void attn_kernel(
    const unsigned short* __restrict__ Q,
    const unsigned short* __restrict__ K,
    const unsigned short* __restrict__ Vt,
    unsigned short* __restrict__ ctx)
{
    // [buf][ K half0 | K half1 | V half0 | V half1 ], each half 4096 shorts
    __shared__ unsigned short KV[2][16384];

    int t = threadIdx.x, w = t >> 6, lane = t & 63;
    int l16 = lane & 15, quad = lane >> 4;
    int r7 = l16 & 7;
    int bh = blockIdx.x;            // XCD = bh % 8 (L2 locality)
    int b_ = bh >> 4, h = bh & 15;
    int ty = blockIdx.y;            // 0..15
    int tile = (ty < 8) ? ty : 23 - ty;   // pairs (y,y+8) sum nch to 17
    int qb = tile * 128 + w * 16;   // wave's 16 q rows within the 128q tile
    int qlast = qb + 15;            // wave's last needed key (causal)
    int nch = tile + 1;             // 128-key chunks staged by the block

    const unsigned short* Kg  = K  + (long)bh * NSEQ * HDIM;
    const unsigned short* Vtg = Vt + (long)bh * HDIM * NSEQ;

    const float log2e = 1.44269504f;
    float slope = exp2f(-0.5f * (float)(h + 1));
    float sc2 = 0.125f * log2e;     // scale * log2(e)
    float ss2 = slope * sc2;

    const unsigned short* qp = Q + ((long)bh * NSEQ + qb + l16) * HDIM + quad * 8;
    bf16x8 aq0 = *(const bf16x8*)qp;
    bf16x8 aq1 = *(const bf16x8*)(qp + 32);

    // alibi C-init, slim form: ci4[r] = slope*(quad*4+r); per-tt add slope*16*tt
    f32x4 ci4;
#pragma unroll
    for (int r = 0; r < 4; r++)
        ci4[r] = slope * (float)(quad * 4 + r);
    float s16 = slope * 16.0f;

    f32x4 lv = {};
    f32x4 o[4] = {};

    // staging: 512 threads x 16B cover 8KB per pass (one 64-key half)
    int row = t >> 3, sp = t & 7, sw = sp ^ (row & 7);
    const unsigned short* gk = Kg + row * HDIM + sw * 8;
    const unsigned short* gv = Vtg + (long)row * NSEQ + sw * 8;

    {   // stage chunk 0 (keys 0..127)
        unsigned short* buf = KV[0];
        load16_lds(gk,             buf + t * 8);
        load16_lds(gk + 64 * HDIM, buf + 4096 + t * 8);
        load16_lds(gv,             buf + 8192 + t * 8);
        load16_lds(gv + 64,        buf + 12288 + t * 8);
    }

    for (int c = 0; c < nch; c++) {
        __syncthreads();
        if (c + 1 < nch) {
            int kb2 = (c + 1) * 128;
            unsigned short* buf = KV[(c + 1) & 1];
            load16_lds(gk + (long)kb2 * HDIM,        buf + t * 8);
            load16_lds(gk + (long)(kb2 + 64) * HDIM, buf + 4096 + t * 8);
            load16_lds(gv + kb2,                     buf + 8192 + t * 8);
            load16_lds(gv + kb2 + 64,                buf + 12288 + t * 8);
        }

#pragma unroll
        for (int hh = 0; hh < 2; hh++) {
            int kb = c * 128 + hh * 64;
            if (kb > qlast) continue;          // wave-uniform causal skip

            const unsigned short* Ks = KV[c & 1] + hh * 4096;
            const unsigned short* Vs = KV[c & 1] + 8192 + hh * 4096;

            // ---- S^T = K·Q^T + alibi (one 16-q slice per wave)
            f32x4 s[4];
            __builtin_amdgcn_s_setprio(1);
#pragma unroll
            for (int tt = 0; tt < 4; tt++) {
                int rr = tt * 16 + l16;
                bf16x8 k0 = *(const bf16x8*)(Ks + (rr * 8 + (quad ^ r7)) * 8);
                bf16x8 k1 = *(const bf16x8*)(Ks + (rr * 8 + ((quad + 4) ^ r7)) * 8);
                f32x4 cz;
#pragma unroll
                for (int r = 0; r < 4; r++)
                    cz[r] = ci4[r] + (float)tt * s16;
                f32x4 z = MFMA32(k0, aq0, cz);
                s[tt] = MFMA32(k1, aq1, z);
            }
            __builtin_amdgcn_s_setprio(0);

            float mrow = ss2 * (float)(qb + l16 - kb);
            unsigned pb[2][4];
            softmax_fixed(s, kb + 63 > qb, qb, kb, sc2, mrow, lv, pb, l16, quad);

            // ---- O^T += V^T·P^T (verified pattern)
            int q2 = quad >> 1, q1b = (quad & 1) << 3;
            __builtin_amdgcn_s_setprio(1);
#pragma unroll
            for (int cb = 0; cb < 4; cb++) {
                int rd = cb * 16 + l16;
                const char* vrow = (const char*)(Vs + rd * 64);
                int x7 = rd & 7;
#pragma unroll
                for (int p = 0; p < 2; p++) {
                    union { bf16x8 v; uint2 u2[2]; } a;
                    int sb0 = 4 * p + q2;
                    int sb1 = 4 * p + 2 + q2;
                    a.u2[0] = *(const uint2*)(vrow + ((sb0 ^ x7) << 4) + q1b);
                    a.u2[1] = *(const uint2*)(vrow + ((sb1 ^ x7) << 4) + q1b);
                    union { unsigned u[4]; bf16x8 v; } bv;
#pragma unroll
                    for (int i = 0; i < 4; i++) bv.u[i] = pb[p][i];
                    o[cb] = MFMA32(a.v, bv.v, o[cb]);
                }
            }
            __builtin_amdgcn_s_setprio(0);
        }
    }

    // ---- final l reduction + normalize, store ctx [b, n=q, h, d]
    {
        float lt = (lv[0] + lv[1]) + (lv[2] + lv[3]);
        lt += __shfl_xor(lt, 16);
        lt += __shfl_xor(lt, 32);
        float inv = 1.0f / lt;
        long base = (((long)b_ * NSEQ + (qb + l16)) * NH + h) * HDIM + quad * 4;
#pragma unroll
        for (int cb = 0; cb < 4; cb++) {
            uint2 u;
            u.x = pack2bf(o[cb][0] * inv, o[cb][1] * inv);
            u.y = pack2bf(o[cb][2] * inv, o[cb][3] * inv);
            *(uint2*)(ctx + base + cb * 16) = u;
        }
    }
}

// ---------------------------------------------------------------------------
// Output projection, 64x128 tile, XCD-bijective swizzle, (256,4). (R2)
// ---------------------------------------------------------------------------
__global__ __launch_bounds__(256, 4) void out_gemm_kernel(
    const unsigned short* __restrict__ A,
    const unsigned short* __restrict__ Bt,
    const float* __restrict__ bias,
    float* __restrict__ out)
{
    __shared__ unsigned short As[2][64 * 32];
    __shared__ unsigned short Bs[2][128 * 32];
    f32x4 acc[2][4] = {};
    int id = blockIdx.y * 8 + blockIdx.x;         // nwg = 64*8 = 512
    id = (id & 7) * 64 + (id >> 3);               // XCD-bijective swizzle
    int m0 = (id >> 3) * 64, n0 = (id & 7) * 128;
    gemm_core_db<2>(A, Bt, m0, n0, &As[0][0], &Bs[0][0], acc);

    int t = threadIdx.x, wave = t >> 6, lane = t & 63;
    int l16 = lane & 15, quad = lane >> 4;
    int wm = wave >> 1, wn = wave & 1;
    int rg0 = m0 + wm * 32, cg0 = n0 + wn * 64;
#pragma unroll
    for (int c = 0; c < 4; c++) {
        float bc = bias[cg0 + c * 16 + l16];
#pragma unroll
        for (int r = 0; r < 2; r++)
#pragma unroll
            for (int reg = 0; reg < 4; reg++)
                out[(long)(rg0 + r * 16 + quad * 4 + reg) * DM + cg0 + c * 16 + l16] =
                    acc[r][c][reg] + bc;
    }
}

// ---------------------------------------------------------------------------
extern "C" void kernel_launch(void* const* d_in, const int* in_sizes, int n_in,
                              void* d_out, int out_size, void* d_ws, size_t ws_size,
                              hipStream_t stream)
{
    const float* x  = (const float*)d_in[0];
    const float* wq = (const float*)d_in[1];
    const float* wk = (const float*)d_in[2];
    const float* wv = (const float*)d_in[3];
    const float* wo = (const float*)d_in[4];
    const float* bo = (const float*)d_in[5];

    char* ws = (char*)d_ws;
    unsigned short* xb    = (unsigned short*)(ws);                 // 8 MiB
    unsigned short* wqkvt = (unsigned short*)(ws + (8L  << 20));   // 6 MiB [3072][1024]
    unsigned short* wot   = (unsigned short*)(ws + (14L << 20));   // 2 MiB
    unsigned short* Qb    = (unsigned short*)(ws + (16L << 20));   // 8 MiB
    unsigned short* Kb    = (unsigned short*)(ws + (24L << 20));   // 8 MiB
    unsigned short* Vt    = (unsigned short*)(ws + (32L << 20));   // 8 MiB
    unsigned short* ctx   = (unsigned short*)(ws + (40L << 20));   // 8 MiB
    float* out = (float*)d_out;

    convert_kernel<<<2048, 256, 0, stream>>>(x, wq, wk, wv, wo, xb, wqkvt, wot);

    qkv_gemm_kernel<<<dim3(3 * DM / 128, MROWS / 128), 256, 0, stream>>>(
        xb, wqkvt, Qb, Kb, Vt);

    attn_kernel<<<dim3(NB * NH, 16), 512, 0, stream>>>(Qb, Kb, Vt, ctx);

    out_gemm_kernel<<<dim3(DM / 128, MROWS / 64), 256, 0, stream>>>(
        ctx, wot, bo, out);
}

// Round 11
// 163.968 us; speedup vs baseline: 1.1102x; 1.0273x over previous
//
#include <hip/hip_runtime.h>
#include <hip/hip_bf16.h>
#include <stdint.h>

#define NH 16
#define HDIM 64
#define NB 2
#define NSEQ 2048
#define DM 1024
#define MROWS (NB * NSEQ)   // 4096

typedef __attribute__((ext_vector_type(8))) short bf16x8;
typedef __attribute__((ext_vector_type(4))) float f32x4;

#define MFMA32(a, b, c) __builtin_amdgcn_mfma_f32_16x16x32_bf16(a, b, c, 0, 0, 0)

static __device__ __forceinline__ unsigned short f2bf(float f) {
    union { float f; unsigned u; } v;
    v.f = f;
    unsigned r = v.u + 0x7fffu + ((v.u >> 16) & 1u);   // RNE
    return (unsigned short)(r >> 16);
}

static __device__ __forceinline__ unsigned pack2bf(float a, float b) {
#if __has_builtin(__builtin_amdgcn_cvt_pk_bf16_f32)
    typedef __attribute__((ext_vector_type(2))) __bf16 bf2_t;
    union { bf2_t v; unsigned u; } c;
    c.v = __builtin_amdgcn_cvt_pk_bf16_f32(a, b);
    return c.u;
#else
    return (unsigned)f2bf(a) | ((unsigned)f2bf(b) << 16);
#endif
}

static __device__ __forceinline__ float fexp2(float x) {
#if __has_builtin(__builtin_amdgcn_exp2f)
    return __builtin_amdgcn_exp2f(x);
#else
    return exp2f(x);
#endif
}

typedef __attribute__((address_space(1))) void* gas_ptr;
typedef __attribute__((address_space(3))) void* las_ptr;

// async global->LDS, 16B per lane. LDS dest must be wave-uniform base + lane*16.
static __device__ __forceinline__ void load16_lds(const void* g, void* l) {
    __builtin_amdgcn_global_load_lds((gas_ptr)(uintptr_t)g, (las_ptr)(uintptr_t)l,
                                     16, 0, 0);
}

// ---------------------------------------------------------------------------
// Convert: x -> bf16 (blocks 0..1023), weights -> bf16 transposed via LDS
// tile transpose (blocks 1024..2047). (unchanged)
// ---------------------------------------------------------------------------
__global__ __launch_bounds__(256) void convert_kernel(
    const float* __restrict__ x,
    const float* __restrict__ wq, const float* __restrict__ wk,
    const float* __restrict__ wv, const float* __restrict__ wo,
    unsigned short* __restrict__ xb,
    unsigned short* __restrict__ wqkvt,
    unsigned short* __restrict__ wot)
{
    __shared__ unsigned short Ts[64][66];
    int t = threadIdx.x;
    int bx = blockIdx.x;
    if (bx < 1024) {
        const float4* xs = (const float4*)x + (long)bx * 1024;
        unsigned short* xd = xb + (long)bx * 4096;
#pragma unroll
        for (int i = 0; i < 4; i++) {
            float4 v = xs[i * 256 + t];
            ushort4 o;
            o.x = f2bf(v.x); o.y = f2bf(v.y); o.z = f2bf(v.z); o.w = f2bf(v.w);
            *(ushort4*)(xd + (i * 256 + t) * 4) = o;
        }
        return;
    }
    int wi = bx - 1024;
    int wsel = wi >> 8;                 // 0..3 = q,k,v,o
    int tile = wi & 255;
    int k0 = (tile >> 4) * 64, c0 = (tile & 15) * 64;
    const float* w = (wsel == 0) ? wq : (wsel == 1) ? wk : (wsel == 2) ? wv : wo;
    int lr = t >> 6, lc = t & 63;
#pragma unroll
    for (int rr = 0; rr < 16; rr++) {
        int row = rr * 4 + lr;
        Ts[row][lc] = f2bf(w[(long)(k0 + row) * DM + c0 + lc]);
    }
    __syncthreads();
    unsigned short* dst = (wsel == 3) ? wot : (wqkvt + (long)wsel * DM * DM);
#pragma unroll
    for (int rr = 0; rr < 16; rr++) {
        int crow = rr * 4 + lr;
        dst[(long)(c0 + crow) * DM + k0 + lc] = Ts[lc][crow];
    }
}

// ---------------------------------------------------------------------------
// DOUBLE-BUFFERED GEMM core (unchanged structure; round-13 swizzle kept).
// ---------------------------------------------------------------------------
template<int MR>
static __device__ __forceinline__ void gemm_core_db(
    const unsigned short* __restrict__ A,
    const unsigned short* __restrict__ Bt,
    int m0, int n0,
    unsigned short* __restrict__ As,   // [2][MR*32*32] shorts
    unsigned short* __restrict__ Bs,   // [2][128*32] shorts
    f32x4 (&acc)[MR][4])
{
    constexpr int MT  = MR * 32;       // M tile rows
    constexpr int ASZ = MT * 32;       // shorts per A buffer
    constexpr int BSZ = 128 * 32;      // shorts per B buffer
    constexpr int NA  = MT / 64;       // A load16 per thread (2 or 1)

    int t = threadIdx.x;
    int lane = t & 63;
    int wave = t >> 6;
    int l16 = lane & 15, quad = lane >> 4;
    int wm = wave >> 1, wn = wave & 1;

    const char* gA[NA];
#pragma unroll
    for (int i = 0; i < NA; i++) {
        int b = i * 256 + t;
        int row = b >> 2, g = (b & 3) ^ ((row >> 1) & 3);
        gA[i] = (const char*)(A + (long)(m0 + row) * DM) + g * 16;
    }
    const char* gB[2];
#pragma unroll
    for (int i = 0; i < 2; i++) {
        int b = i * 256 + t;
        int row = b >> 2, g = (b & 3) ^ ((row >> 1) & 3);
        gB[i] = (const char*)(Bt + (long)(n0 + row) * DM) + g * 16;
    }

    int sread = quad ^ ((l16 >> 1) & 3);
    int faOff = (wm * (MT / 2) + l16) * 32 + sread * 8;
    int fbOff = (wn * 64 + l16) * 32 + sread * 8;

    // stage k=0 into buffer 0
#pragma unroll
    for (int i = 0; i < NA; i++)
        load16_lds(gA[i], (char*)As + i * 4096 + t * 16);
#pragma unroll
    for (int i = 0; i < 2; i++)
        load16_lds(gB[i], (char*)Bs + i * 4096 + t * 16);

    for (int kk = 0; kk < DM; kk += 32) {
        int cur = (kk >> 5) & 1;
        __syncthreads();                       // stage(kk) landed; buf free
        if (kk + 32 < DM) {
            int nxt = cur ^ 1;
            char* abuf = (char*)(As + nxt * ASZ);
            char* bbuf = (char*)(Bs + nxt * BSZ);
#pragma unroll
            for (int i = 0; i < NA; i++)
                load16_lds(gA[i] + (kk + 32) * 2, abuf + i * 4096 + t * 16);
#pragma unroll
            for (int i = 0; i < 2; i++)
                load16_lds(gB[i] + (kk + 32) * 2, bbuf + i * 4096 + t * 16);
        }
        const unsigned short* fa = As + cur * ASZ + faOff;
        const unsigned short* fb = Bs + cur * BSZ + fbOff;
        bf16x8 af[MR], bf[4];
#pragma unroll
        for (int r = 0; r < MR; r++) af[r] = *(const bf16x8*)(fa + r * 16 * 32);
#pragma unroll
        for (int c = 0; c < 4; c++) bf[c] = *(const bf16x8*)(fb + c * 16 * 32);
#pragma unroll
        for (int r = 0; r < MR; r++)
#pragma unroll
            for (int c = 0; c < 4; c++)
                acc[r][c] = MFMA32(af[r], bf[c], acc[r][c]);
    }
}

// ---------------------------------------------------------------------------
// Fused QKV GEMM, 128x128 tile, XCD-bijective swizzle (R2-verified).
// ---------------------------------------------------------------------------
__global__ __launch_bounds__(256, 3) void qkv_gemm_kernel(
    const unsigned short* __restrict__ A,
    const unsigned short* __restrict__ Bt,
    unsigned short* __restrict__ Qo, unsigned short* __restrict__ Ko,
    unsigned short* __restrict__ Vt)
{
    __shared__ unsigned short As[2][128 * 32];
    __shared__ unsigned short Bs[2][128 * 32];
    __shared__ unsigned short Tw[4][16][72];

    f32x4 acc[4][4] = {};
    int id = blockIdx.y * 24 + blockIdx.x;        // nwg = 32*24 = 768
    id = (id & 7) * 96 + (id >> 3);               // XCD-bijective swizzle
    int m0 = (id / 24) * 128, n0 = (id % 24) * 128;
    gemm_core_db<4>(A, Bt, m0, n0, &As[0][0], &Bs[0][0], acc);

    int t = threadIdx.x, wave = t >> 6, lane = t & 63;
    int l16 = lane & 15, quad = lane >> 4;
    int wm = wave >> 1, wn = wave & 1;
    int rg0 = m0 + wm * 64;
    int cg0 = n0 + wn * 64;
    int z = cg0 >> 10;
    int b_ = rg0 >> 11;
    int nb0 = rg0 & (NSEQ - 1);
    int h = (cg0 & 1023) >> 6;
    long bh = (long)(b_ * NH + h);

    if (z < 2) {
        unsigned short* dst = (z == 0 ? Qo : Ko) + bh * NSEQ * HDIM;
#pragma unroll
        for (int r = 0; r < 4; r++)
#pragma unroll
            for (int reg = 0; reg < 4; reg++) {
                long rowb = (long)(nb0 + r * 16 + quad * 4 + reg) * HDIM;
#pragma unroll
                for (int c = 0; c < 4; c++)
                    dst[rowb + c * 16 + l16] = f2bf(acc[r][c][reg]);
            }
    } else {
        unsigned short* dst = Vt + bh * HDIM * NSEQ;
#pragma unroll
        for (int c = 0; c < 4; c++) {
#pragma unroll
            for (int r = 0; r < 4; r++) {
                ushort4 u;
                u.x = f2bf(acc[r][c][0]); u.y = f2bf(acc[r][c][1]);
                u.z = f2bf(acc[r][c][2]); u.w = f2bf(acc[r][c][3]);
                *(ushort4*)&Tw[wave][l16][r * 16 + quad * 4] = u;   // [hd][n]
            }
#pragma unroll
            for (int j = 0; j < 4; j++) {
                int lrow = j * 4 + quad;
                ushort4 u = *(const ushort4*)&Tw[wave][lrow][l16 * 4];
                *(ushort4*)(dst + (long)(c * 16 + lrow) * NSEQ + nb0 + l16 * 4) = u;
            }
        }
    }
}

// ---------------------------------------------------------------------------
// fixed-shift softmax, in-place exp (R2-verified).
// ---------------------------------------------------------------------------
static __device__ __forceinline__ void softmax_fixed(
    f32x4* s, bool mask, int qb, int kb, float sc2, float mrow,
    f32x4& l_vec, unsigned pbu[2][4], int l16, int quad)
{
    if (mask) {
        int fdm = qb + l16 - kb - quad * 4;   // key offset tt*16+r must be <= fdm
#pragma unroll
        for (int tt = 0; tt < 4; tt++)
#pragma unroll
            for (int r = 0; r < 4; r++)
                if (tt * 16 + r > fdm) s[tt][r] = -3e38f;
    }
#pragma unroll
    for (int tt = 0; tt < 4; tt++)
#pragma unroll
        for (int r = 0; r < 4; r++)
            s[tt][r] = fexp2(s[tt][r] * sc2 - mrow);   // v_fma + v_exp, in-place
#pragma unroll
    for (int r = 0; r < 4; r++)
        l_vec[r] += (s[0][r] + s[1][r]) + (s[2][r] + s[3][r]);

#pragma unroll
    for (int p = 0; p < 2; p++) {
        pbu[p][0] = pack2bf(s[2 * p][0],     s[2 * p][1]);
        pbu[p][1] = pack2bf(s[2 * p][2],     s[2 * p][3]);
        pbu[p][2] = pack2bf(s[2 * p + 1][0], s[2 * p + 1][1]);
        pbu[p][3] = pack2bf(s[2 * p + 1][2], s[2 * p + 1][3]);
    }
}

// ---------------------------------------------------------------------------
// Flash attention v11 (R2/R6-verified best, 165.7 us total): 128-key chunks
// per barrier, paired t1/t0 blocks, K+V staged via global_load_lds dbuf.
// Session evidence locks this structure: direct-global V (R5, 76us), 32q/wave
// read-sharing (R7, 48us), un-paired 64-key (R8, 49us), counted-vmcnt
// pipeline (R9, 56us), balanced 128q tiles (R10, +2.7us) ALL lost to it.
// Floor is VALU (~17us/CU) + MFMA overlap; barrier imbalance is hidden by
// 2-blocks/CU overlap. THIS ROUND's only delta vs R6: cinit[4][4] alibi
// C-init precomputed in registers (VGPR 60->~72, budget 128) -- deletes
// 16 v_add per half-tile from the hot loop.
// ---------------------------------------------------------------------------
__global__ __launch_bounds__(512, 4) void attn_kernel(
    const unsigned short* __restrict__ Q,
    const unsigned short* __restrict__ K,
    const unsigned short* __restrict__ Vt,
    unsigned short* __restrict__ ctx)
{
    // [buf][ K half0 | K half1 | V half0 | V half1 ], each half 4096 shorts
    __shared__ unsigned short KV[2][16384];

    int t = threadIdx.x, w = t >> 6, lane = t & 63;
    int l16 = lane & 15, quad = lane >> 4;
    int r7 = l16 & 7;
    int bh = blockIdx.x;            // XCD = bh % 8 (L2 locality)
    int b_ = bh >> 4, h = bh & 15;
    int pr = blockIdx.y;            // pair id 0..15
    int t1 = 31 - pr, t0 = pr;
    bool isT0 = (w >= 4);
    int myTile = isT0 ? t0 : t1;
    int qb = myTile * 64 + (w & 3) * 16;
    int qlast = qb + 15;            // wave's last needed key (causal)
    int nch = (t1 + 2) >> 1;        // 128-key chunks staged by the block

    const unsigned short* Kg  = K  + (long)bh * NSEQ * HDIM;
    const unsigned short* Vtg = Vt + (long)bh * HDIM * NSEQ;

    const float log2e = 1.44269504f;
    float slope = exp2f(-0.5f * (float)(h + 1));
    float sc2 = 0.125f * log2e;     // scale * log2(e)
    float ss2 = slope * sc2;

    const unsigned short* qp = Q + ((long)bh * NSEQ + qb + l16) * HDIM + quad * 8;
    bf16x8 aq0 = *(const bf16x8*)qp;
    bf16x8 aq1 = *(const bf16x8*)(qp + 32);

    // alibi C-init (chunk-constant): cinit[tt][r] = slope*(tt*16+quad*4+r)
    // precomputed in registers (16 VGPR, budget has headroom: R5 showed 60/128)
    f32x4 cinit[4];
#pragma unroll
    for (int tt = 0; tt < 4; tt++)
#pragma unroll
        for (int r = 0; r < 4; r++)
            cinit[tt][r] = slope * (float)(tt * 16 + quad * 4 + r);

    f32x4 lv = {};
    f32x4 o[4] = {};

    // staging: 512 threads x 16B cover 8KB per pass (one 64-key half)
    int row = t >> 3, sp = t & 7, sw = sp ^ (row & 7);
    const unsigned short* gk = Kg + row * HDIM + sw * 8;
    const unsigned short* gv = Vtg + (long)row * NSEQ + sw * 8;

    {   // stage chunk 0 (keys 0..127)
        unsigned short* buf = KV[0];
        load16_lds(gk,             buf + t * 8);
        load16_lds(gk + 64 * HDIM, buf + 4096 + t * 8);
        load16_lds(gv,             buf + 8192 + t * 8);
        load16_lds(gv + 64,        buf + 12288 + t * 8);
    }

    for (int c = 0; c < nch; c++) {
        __syncthreads();
        if (c + 1 < nch) {
            int kb2 = (c + 1) * 128;
            unsigned short* buf = KV[(c + 1) & 1];
            load16_lds(gk + (long)kb2 * HDIM,        buf + t * 8);
            load16_lds(gk + (long)(kb2 + 64) * HDIM, buf + 4096 + t * 8);
            load16_lds(gv + kb2,                     buf + 8192 + t * 8);
            load16_lds(gv + kb2 + 64,                buf + 12288 + t * 8);
        }

#pragma unroll
        for (int hh = 0; hh < 2; hh++) {
            int kb = c * 128 + hh * 64;
            if (kb > qlast) continue;          // wave-uniform causal skip

            const unsigned short* Ks = KV[c & 1] + hh * 4096;
            const unsigned short* Vs = KV[c & 1] + 8192 + hh * 4096;

            // ---- S^T = K·Q^T + alibi (one 16-q slice per wave)
            f32x4 s[4];
            __builtin_amdgcn_s_setprio(1);
#pragma unroll
            for (int tt = 0; tt < 4; tt++) {
                int rr = tt * 16 + l16;
                bf16x8 k0 = *(const bf16x8*)(Ks + (rr * 8 + (quad ^ r7)) * 8);
                bf16x8 k1 = *(const bf16x8*)(Ks + (rr * 8 + ((quad + 4) ^ r7)) * 8);
                f32x4 z = MFMA32(k0, aq0, cinit[tt]);
                s[tt] = MFMA32(k1, aq1, z);
            }
            __builtin_amdgcn_s_setprio(0);

            float mrow = ss2 * (float)(qb + l16 - kb);
            unsigned pb[2][4];
            softmax_fixed(s, kb + 63 > qb, qb, kb, sc2, mrow, lv, pb, l16, quad);

            // ---- O^T += V^T·P^T (verified pattern)
            int q2 = quad >> 1, q1b = (quad & 1) << 3;
            __builtin_amdgcn_s_setprio(1);
#pragma unroll
            for (int cb = 0; cb < 4; cb++) {
                int rd = cb * 16 + l16;
                const char* vrow = (const char*)(Vs + rd * 64);
                int x7 = rd & 7;
#pragma unroll
                for (int p = 0; p < 2; p++) {
                    union { bf16x8 v; uint2 u2[2]; } a;
                    int sb0 = 4 * p + q2;
                    int sb1 = 4 * p + 2 + q2;
                    a.u2[0] = *(const uint2*)(vrow + ((sb0 ^ x7) << 4) + q1b);
                    a.u2[1] = *(const uint2*)(vrow + ((sb1 ^ x7) << 4) + q1b);
                    union { unsigned u[4]; bf16x8 v; } bv;
#pragma unroll
                    for (int i = 0; i < 4; i++) bv.u[i] = pb[p][i];
                    o[cb] = MFMA32(a.v, bv.v, o[cb]);
                }
            }
            __builtin_amdgcn_s_setprio(0);
        }
    }

    // ---- final l reduction + normalize, store ctx [b, n=q, h, d]
    {
        float lt = (lv[0] + lv[1]) + (lv[2] + lv[3]);
        lt += __shfl_xor(lt, 16);
        lt += __shfl_xor(lt, 32);
        float inv = 1.0f / lt;
        long base = (((long)b_ * NSEQ + (qb + l16)) * NH + h) * HDIM + quad * 4;
#pragma unroll
        for (int cb = 0; cb < 4; cb++) {
            uint2 u;
            u.x = pack2bf(o[cb][0] * inv, o[cb][1] * inv);
            u.y = pack2bf(o[cb][2] * inv, o[cb][3] * inv);
            *(uint2*)(ctx + base + cb * 16) = u;
        }
    }
}

// ---------------------------------------------------------------------------
// Output projection, 64x128 tile, XCD-bijective swizzle, (256,4). (R2)
// ---------------------------------------------------------------------------
__global__ __launch_bounds__(256, 4) void out_gemm_kernel(
    const unsigned short* __restrict__ A,
    const unsigned short* __restrict__ Bt,
    const float* __restrict__ bias,
    float* __restrict__ out)
{
    __shared__ unsigned short As[2][64 * 32];
    __shared__ unsigned short Bs[2][128 * 32];
    f32x4 acc[2][4] = {};
    int id = blockIdx.y * 8 + blockIdx.x;         // nwg = 64*8 = 512
    id = (id & 7) * 64 + (id >> 3);               // XCD-bijective swizzle
    int m0 = (id >> 3) * 64, n0 = (id & 7) * 128;
    gemm_core_db<2>(A, Bt, m0, n0, &As[0][0], &Bs[0][0], acc);

    int t = threadIdx.x, wave = t >> 6, lane = t & 63;
    int l16 = lane & 15, quad = lane >> 4;
    int wm = wave >> 1, wn = wave & 1;
    int rg0 = m0 + wm * 32, cg0 = n0 + wn * 64;
#pragma unroll
    for (int c = 0; c < 4; c++) {
        float bc = bias[cg0 + c * 16 + l16];
#pragma unroll
        for (int r = 0; r < 2; r++)
#pragma unroll
            for (int reg = 0; reg < 4; reg++)
                out[(long)(rg0 + r * 16 + quad * 4 + reg) * DM + cg0 + c * 16 + l16] =
                    acc[r][c][reg] + bc;
    }
}

// ---------------------------------------------------------------------------
extern "C" void kernel_launch(void* const* d_in, const int* in_sizes, int n_in,
                              void* d_out, int out_size, void* d_ws, size_t ws_size,
                              hipStream_t stream)
{
    const float* x  = (const float*)d_in[0];
    const float* wq = (const float*)d_in[1];
    const float* wk = (const float*)d_in[2];
    const float* wv = (const float*)d_in[3];
    const float* wo = (const float*)d_in[4];
    const float* bo = (const float*)d_in[5];

    char* ws = (char*)d_ws;
    unsigned short* xb    = (unsigned short*)(ws);                 // 8 MiB
    unsigned short* wqkvt = (unsigned short*)(ws + (8L  << 20));   // 6 MiB [3072][1024]
    unsigned short* wot   = (unsigned short*)(ws + (14L << 20));   // 2 MiB
    unsigned short* Qb    = (unsigned short*)(ws + (16L << 20));   // 8 MiB
    unsigned short* Kb    = (unsigned short*)(ws + (24L << 20));   // 8 MiB
    unsigned short* Vt    = (unsigned short*)(ws + (32L << 20));   // 8 MiB
    unsigned short* ctx   = (unsigned short*)(ws + (40L << 20));   // 8 MiB
    float* out = (float*)d_out;

    convert_kernel<<<2048, 256, 0, stream>>>(x, wq, wk, wv, wo, xb, wqkvt, wot);

    qkv_gemm_kernel<<<dim3(3 * DM / 128, MROWS / 128), 256, 0, stream>>>(
        xb, wqkvt, Qb, Kb, Vt);

    attn_kernel<<<dim3(NB * NH, 16), 512, 0, stream>>>(Qb, Kb, Vt, ctx);

    out_gemm_kernel<<<dim3(DM / 128, MROWS / 64), 256, 0, stream>>>(
        ctx, wot, bo, out);
}